// Round 5
// baseline (426.111 us; speedup 1.0000x reference)
//
#include <hip/hip_runtime.h>

// ROI adaptive average pooling — R7: DOUBLED-STORE PROBE (not an optimization).
// B=8, C=1024, HW=14, N=512, FS=14, SCALE=1/16.
//
// Purpose: discriminate two theories that both explain six consecutive null
// results (R3: LDS/2 + conflict-free; R4: reads/16, blocks/16; R6: nt stores):
//   H1: kernel ~150us, store stream capped at ~2.7 TB/s effective.
//   H2: kernel already at ~65us HBM-write floor; the residual ~145us of
//       dur_us is fixed harness time (dozens of tiny reset() dispatches).
// Method: compute outputs once into registers, then store the SAME correct
// values TWICE (pass 1, compiler memory barrier, pass 2). Adds exactly
// +411 MB store traffic, nothing else. Readout:
//   H1 -> dur_us +~150 (=> ~570), kernel surfaces in top-5 with counters.
//   H2 -> dur_us +~65  (=> ~485), kernel stays hidden.
// Next round reverts to R6 regardless of outcome.

#define FS_      14
#define PER_CH   196               // 14*14
#define C_       1024
#define CPB      32                // channels per block
#define QPC      49                // quads per channel (196/4)
#define NSTAGE4  (CPB * PER_CH / 4)  // 1568 float4 to stage
#define ACT      245               // active compute threads = 5*49

typedef float vfloat4 __attribute__((ext_vector_type(4)));

#if defined(__has_builtin)
# if __has_builtin(__builtin_amdgcn_global_load_lds)
#  define USE_GLL 1
# endif
# if __has_builtin(__builtin_nontemporal_store)
#  define USE_NT 1
# endif
#endif

static __device__ __forceinline__ void store_out(vfloat4 v, vfloat4* p) {
#if defined(USE_NT)
    __builtin_nontemporal_store(v, p);
#else
    *p = v;
#endif
}

__global__ __launch_bounds__(256) void roi_pool_kernel(
    const float* __restrict__ tensor,
    const float* __restrict__ roi,
    float* __restrict__ out)
{
    __shared__ float s_plane[CPB * PER_CH + 4];   // 25,104 B (+4 zeroed pad)
    __shared__ alignas(16) int   s_o00[PER_CH], s_o10[PER_CH];  // byte offsets
    __shared__ alignas(16) float s_mw[PER_CH], s_mh[PER_CH], s_inv[PER_CH];

    const unsigned bx = blockIdx.x;
    const unsigned n  = bx >> 5;            // ROI index
    const unsigned c0 = (bx & 31u) * CPB;   // first channel of this block

    // ROI row [batch_idx, x1, y1, x2, y2] in 224-px coords (uniform -> scalar).
    const float* r = roi + n * 5;
    const int fm = (int)r[0];
    const int x1 = max((int)floorf(r[1] * 0.0625f), 0);
    const int y1 = max((int)floorf(r[2] * 0.0625f), 0);
    const int x2 = min((int)ceilf(r[3] * 0.0625f), FS_);
    const int y2 = min((int)ceilf(r[4] * 0.0625f), FS_);
    const unsigned Lh = (unsigned)(x2 - x1);   // 1..14 guaranteed
    const unsigned Lw = (unsigned)(y2 - y1);

    const unsigned tid = threadIdx.x;

    // ---- Phase 1a: geometry tables (196 positions), byte offsets into a plane.
    if (tid < PER_CH) {
        const unsigned p = tid;
        const unsigned i = p / 14u;
        const unsigned j = p - i * 14u;
        const unsigned h0 = (i * Lh) / 14u;
        const unsigned h1 = ((i + 1u) * Lh + 13u) / 14u;
        const unsigned w0 = (j * Lw) / 14u;
        const unsigned w1 = ((j + 1u) * Lw + 13u) / 14u;
        const int dh = (int)(h1 - h0) - 1;     // 0 or 1
        const int dw = (int)(w1 - w0) - 1;     // 0 or 1
        const int a00 = (x1 + (int)h0) * FS_ + (y1 + (int)w0);
        s_o00[p] = a00 * 4;
        s_o10[p] = (a00 + FS_ * dh) * 4;
        s_mw[p]  = (float)dw;
        s_mh[p]  = (float)dh;
        const int cnt = (dh + 1) * (dw + 1);   // 1, 2, or 4
        s_inv[p] = (cnt == 1) ? 1.0f : ((cnt == 2) ? 0.5f : 0.25f);
    } else if (tid < PER_CH + 4u) {
        // Zero the overread pad — MUST be deterministic (0 * pad must be 0).
        s_plane[CPB * PER_CH + (tid - PER_CH)] = 0.0f;
    }

    // ---- Phase 1b: stage the 32 contiguous input planes (coalesced float4).
    const float4* __restrict__ src4 =
        (const float4*)(tensor + ((size_t)fm * C_ + c0) * PER_CH);
    float4* __restrict__ dst4 = (float4*)s_plane;
#pragma unroll
    for (unsigned k = 0; k < 7; ++k) {
        unsigned fi = k * 256u + tid;
        if (fi < NSTAGE4) {
#if defined(USE_GLL)
            __builtin_amdgcn_global_load_lds(
                (const __attribute__((address_space(1))) void*)(src4 + fi),
                (__attribute__((address_space(3))) void*)(dst4 + fi),
                16, 0, 0);
#else
            dst4[fi] = src4[fi];
#endif
        }
    }

    __syncthreads();

    // ---- Phase 2: compute all 7 quads into registers, then store TWICE.
    if (tid < ACT) {
        const unsigned tc = tid / QPC;         // 0..4
        const unsigned q  = tid - tc * QPC;    // fixed across iterations

        const int4   O00 = ((const int4*)s_o00)[q];
        const int4   O10 = ((const int4*)s_o10)[q];
        const float4 MW  = ((const float4*)s_mw)[q];
        const float4 MH  = ((const float4*)s_mh)[q];
        const float4 INV = ((const float4*)s_inv)[q];

        vfloat4* __restrict__ out4 =
            (vfloat4*)(out + ((size_t)n * C_ + c0) * PER_CH);

        vfloat4 ov[7];

#pragma unroll
        for (unsigned it = 0; it < 7; ++it) {
            const unsigned cl = it * 5u + tc;  // local channel
            if (cl >= CPB) continue;           // only trims the last iteration
            const char* pb = (const char*)s_plane + cl * (PER_CH * 4);

            vfloat4 o;
            {
                const char* p0 = pb + O00.x;
                const char* p1 = pb + O10.x;
                const float v00 = *(const float*)(p0);
                const float v01 = *(const float*)(p0 + 4);  // ds_read2_b32
                const float v10 = *(const float*)(p1);
                const float v11 = *(const float*)(p1 + 4);
                o.x = (fmaf(MW.x, v01, v00) + MH.x * fmaf(MW.x, v11, v10)) * INV.x;
            }
            {
                const char* p0 = pb + O00.y;
                const char* p1 = pb + O10.y;
                const float v00 = *(const float*)(p0);
                const float v01 = *(const float*)(p0 + 4);
                const float v10 = *(const float*)(p1);
                const float v11 = *(const float*)(p1 + 4);
                o.y = (fmaf(MW.y, v01, v00) + MH.y * fmaf(MW.y, v11, v10)) * INV.y;
            }
            {
                const char* p0 = pb + O00.z;
                const char* p1 = pb + O10.z;
                const float v00 = *(const float*)(p0);
                const float v01 = *(const float*)(p0 + 4);
                const float v10 = *(const float*)(p1);
                const float v11 = *(const float*)(p1 + 4);
                o.z = (fmaf(MW.z, v01, v00) + MH.z * fmaf(MW.z, v11, v10)) * INV.z;
            }
            {
                const char* p0 = pb + O00.w;
                const char* p1 = pb + O10.w;
                const float v00 = *(const float*)(p0);
                const float v01 = *(const float*)(p0 + 4);
                const float v10 = *(const float*)(p1);
                const float v11 = *(const float*)(p1 + 4);
                o.w = (fmaf(MW.w, v01, v00) + MH.w * fmaf(MW.w, v11, v10)) * INV.w;
            }
            ov[it] = o;
        }

        // Store pass 1 (+411 MB probe traffic).
#pragma unroll
        for (unsigned it = 0; it < 7; ++it) {
            const unsigned cl = it * 5u + tc;
            if (cl >= CPB) continue;
            store_out(ov[it], &out4[it * ACT + tid]);
        }

        // Compiler memory barrier: pass 1 stores cannot be dead-store
        // eliminated against pass 2.
        asm volatile("" ::: "memory");

        // Store pass 2 (the surviving, correct values — same addresses).
#pragma unroll
        for (unsigned it = 0; it < 7; ++it) {
            const unsigned cl = it * 5u + tc;
            if (cl >= CPB) continue;
            store_out(ov[it], &out4[it * ACT + tid]);
        }
    }
}

extern "C" void kernel_launch(void* const* d_in, const int* in_sizes, int n_in,
                              void* d_out, int out_size, void* d_ws, size_t ws_size,
                              hipStream_t stream) {
    const float* tensor = (const float*)d_in[0];   // [8,1024,14,14] f32
    const float* roi    = (const float*)d_in[1];   // [512,5] f32
    float* out = (float*)d_out;                    // [512,1024,14,14] f32

    const int blocks = (out_size / (CPB * PER_CH));  // 512 * 32 = 16,384
    roi_pool_kernel<<<blocks, 256, 0, stream>>>(tensor, roi, out);
}